// Round 10
// baseline (297.264 us; speedup 1.0000x reference)
//
#include <hip/hip_runtime.h>
#include <cstdint>
#include <cstddef>

#define NT 256
constexpr int SHIFT  = 7;                 // fine bucket = dst >> 7 (128 nodes)
constexpr int NBK    = 1024;              // allocated fine buckets
constexpr int BMASK  = (1 << SHIFT) - 1;  // 127
constexpr int EPB    = 6400;              // edges per partition block (LDS stage)
constexpr int NPR    = 512;               // padded run count (nPB=500)
constexpr int TSPLIT = 50000;             // src tile split (3.2MB bf16 halves)
constexpr int STCAP  = 6144;              // b_k LDS stage capacity

__device__ __forceinline__ float sigf(float v) {
    return 1.0f / (1.0f + __expf(-v));
}
__device__ __forceinline__ float bf2f(unsigned short u) {
    return __uint_as_float((unsigned)u << 16);
}
__device__ __forceinline__ unsigned short f2bf(float f) {   // round-nearest-even
    unsigned u = __float_as_uint(f);
    return (unsigned short)((u + 0x7fffu + ((u >> 16) & 1u)) >> 16);
}

// ---------------- fused partition: LDS local sort, coalesced writes ----------
// Meta output is a SINGLE block-major contiguous array runcntT[b][f] (4 KB
// burst per block) — no strided dword scatter, no global atomics.
__global__ __launch_bounds__(NT)
void part_k(const int* __restrict__ src, const int* __restrict__ dst,
            unsigned* __restrict__ part, int* __restrict__ runcntT,
            int e_total, int nPB)
{
    __shared__ unsigned stage[EPB];      // 25.6 KB
    __shared__ int hist[NBK];            // 4 KB
    __shared__ int curs[NBK];            // 4 KB
    __shared__ int tsum[NT];             // 1 KB
    const int b    = blockIdx.x;
    const int t    = threadIdx.x;
    const int base = b * EPB;
    const int nh   = min(EPB, e_total - base);

    for (int i = t; i < NBK; i += NT) hist[i] = 0;
    __syncthreads();
    for (int i = t; i < nh; i += NT)
        atomicAdd(&hist[dst[base + i] >> SHIFT], 1);
    __syncthreads();

    // block-major meta write: contiguous 4 KB
    for (int i = t; i < NBK; i += NT)
        runcntT[(size_t)b * NBK + i] = hist[i];

    // exclusive scan of hist[1024]: 4 buckets per thread + 256-wide scan
    const int f0 = 4 * t;
    int h0 = hist[f0], h1 = hist[f0 + 1], h2 = hist[f0 + 2], h3 = hist[f0 + 3];
    int incl = h0 + h1 + h2 + h3;
    tsum[t] = incl;
    __syncthreads();
    for (int off = 1; off < NT; off <<= 1) {
        int add = (t >= off) ? tsum[t - off] : 0;
        __syncthreads();
        tsum[t] += add;
        __syncthreads();
    }
    int ex = tsum[t] - incl;             // exclusive over 4-groups
    curs[f0]     = ex;
    curs[f0 + 1] = ex + h0;
    curs[f0 + 2] = ex + h0 + h1;
    curs[f0 + 3] = ex + h0 + h1 + h2;
    __syncthreads();

    // scatter into LDS stage in bucket order
    for (int i = t; i < nh; i += NT) {
        int d = dst[base + i];
        int s = src[base + i];
        int f = d >> SHIFT;
        int r = atomicAdd(&curs[f], 1);
        stage[r] = ((unsigned)s << SHIFT) | (unsigned)(d & BMASK);
    }
    __syncthreads();

    // coalesced write-out of the block's sorted region
    for (int i = t; i < nh; i += NT) part[base + i] = stage[i];
}

// ---------------- fused transpose + per-block prefix scan ----------------
// runcntT[b][f] (block-major) -> runcnt[f][b], runstart[f][b] = b*EPB +
// prefix_{f'<f} runcntT[b][f']; totcnt[f] += per-tile partial sums.
// Grid: ceil(nPB/32) blocks; 32x32 LDS tiles, coalesced both sides.
__global__ __launch_bounds__(NT)
void xpose_k(const int* __restrict__ runcntT, int* __restrict__ runstart,
             int* __restrict__ runcnt, int* __restrict__ totcnt, int nPB)
{
    __shared__ int tile[32][33];
    __shared__ int outS[32][33];
    __shared__ int pref[32];
    const int t  = threadIdx.x;
    const int b0 = blockIdx.x * 32;
    const int r  = t >> 3;           // 0..31
    const int c0 = (t & 7) * 4;      // 0,4,..28
    if (t < 32) pref[t] = 0;
    __syncthreads();

    for (int fc = 0; fc < NBK / 32; ++fc) {
        const int f0 = fc * 32;
        int b = b0 + r;
        if (b < nPB) {
            const int* p = &runcntT[(size_t)b * NBK + f0 + c0];
            tile[r][c0]     = p[0];
            tile[r][c0 + 1] = p[1];
            tile[r][c0 + 2] = p[2];
            tile[r][c0 + 3] = p[3];
        } else {
            tile[r][c0] = 0; tile[r][c0 + 1] = 0;
            tile[r][c0 + 2] = 0; tile[r][c0 + 3] = 0;
        }
        __syncthreads();
        if (t < 32) {
            int p = pref[t];
            int bb = (b0 + t) * EPB;
            for (int c = 0; c < 32; ++c) {
                outS[c][t] = bb + p;
                p += tile[t][c];
            }
            pref[t] = p;
            // totcnt partial sum for f = f0 + t over this tile's 32 b's
            int s = 0;
            for (int rr = 0; rr < 32; ++rr) s += tile[rr][t];
            if (s) atomicAdd(&totcnt[f0 + t], s);
        }
        __syncthreads();
        int f = f0 + r;
        for (int j = 0; j < 4; ++j) {
            int b2 = b0 + c0 + j;
            if (b2 < nPB) {
                runstart[(size_t)f * nPB + b2] = outS[r][c0 + j];
                runcnt  [(size_t)f * nPB + b2] = tile[c0 + j][r];
            }
        }
        __syncthreads();
    }
}

// exclusive scan of totcnt[1024] -> fbase[1024] (single block)
__global__ __launch_bounds__(1024)
void tscan_k(const int* __restrict__ totcnt, int* __restrict__ fbase)
{
    __shared__ int s[1024];
    int t = threadIdx.x;
    int v = totcnt[t];
    s[t] = v;
    __syncthreads();
    for (int off = 1; off < 1024; off <<= 1) {
        int add = (t >= off) ? s[t - off] : 0;
        __syncthreads();
        s[t] += add;
        __syncthreads();
    }
    fbase[t] = s[t] - v;
}

// per-bucket: coalesced run copy -> LDS stage; dual histogram/scan -> row_ptr,
// mptr; 2-cursor fill -> col ([tile0 | tile1] per node)
__global__ __launch_bounds__(NT)
void b_k(const unsigned* __restrict__ part, const int* __restrict__ runstart,
         const int* __restrict__ runcnt, const int* __restrict__ fbase,
         int* __restrict__ row_ptr, int* __restrict__ mptr,
         int* __restrict__ col, int nPB, int n)
{
    constexpr int NB2 = 1 << SHIFT;      // 128
    __shared__ unsigned stage[STCAP];    // 24 KB
    __shared__ int rss[NPR], rcs[NPR], lof[NPR];   // 6 KB
    __shared__ int ssum[NT];
    __shared__ int d0[NB2], dt[NB2], sc[NB2], c0[NB2], c1[NB2];
    const int f = blockIdx.x;
    const int t = threadIdx.x;

    // run metadata, 2 per thread + exclusive scan of run lengths -> LDS offsets
    const int l0 = 2 * t, l1 = 2 * t + 1;
    int rc0 = (l0 < nPB) ? runcnt[f * nPB + l0] : 0;
    int rc1 = (l1 < nPB) ? runcnt[f * nPB + l1] : 0;
    rss[l0] = (l0 < nPB) ? runstart[f * nPB + l0] : 0;
    rss[l1] = (l1 < nPB) ? runstart[f * nPB + l1] : 0;
    rcs[l0] = rc0;
    rcs[l1] = rc1;
    int incl = rc0 + rc1;
    ssum[t] = incl;
    __syncthreads();
    for (int off = 1; off < NT; off <<= 1) {
        int add = (t >= off) ? ssum[t - off] : 0;
        __syncthreads();
        ssum[t] += add;
        __syncthreads();
    }
    int ex = ssum[t] - incl;
    lof[l0] = ex;
    lof[l1] = ex + rc0;
    __syncthreads();
    const int tot = ssum[NT - 1];

    if (t < NB2) { d0[t] = 0; dt[t] = 0; }
    __syncthreads();

    if (tot <= STCAP) {
        // coalesced copy: 8 threads per run, 32 runs in flight
        const int lane = t & 7;
        const int rg   = t >> 3;
        for (int chunk = 0; chunk < nPB; chunk += 32) {
            int r = chunk + rg;
            if (r < nPB) {
                int s0 = rss[r], c = rcs[r], lo = lof[r];
                for (int i = lane; i < c; i += 8)
                    stage[lo + i] = part[s0 + i];
            }
        }
        __syncthreads();
        for (int i = t; i < tot; i += NT) {
            unsigned p = stage[i];
            int l = p & BMASK;
            atomicAdd(&dt[l], 1);
            if ((int)(p >> SHIFT) < TSPLIT) atomicAdd(&d0[l], 1);
        }
    } else {
        for (int r = t; r < nPB; r += NT) {
            int s0 = rss[r], c = rcs[r];
            for (int i = 0; i < c; ++i) {
                unsigned p = part[s0 + i];
                int l = p & BMASK;
                atomicAdd(&dt[l], 1);
                if ((int)(p >> SHIFT) < TSPLIT) atomicAdd(&d0[l], 1);
            }
        }
    }
    __syncthreads();

    if (t < NB2) sc[t] = dt[t];
    __syncthreads();
    for (int off = 1; off < NB2; off <<= 1) {
        int add = (t >= off && t < NB2) ? sc[t - off] : 0;
        __syncthreads();
        if (t < NB2) sc[t] += add;
        __syncthreads();
    }
    if (t < NB2) {
        int excl = sc[t] - dt[t];
        int st0  = fbase[f] + excl;
        int node = (f << SHIFT) + t;
        if (node <= n) row_ptr[node] = st0;
        if (node <  n) mptr[node]    = st0 + d0[t];
        c0[t] = st0;
        c1[t] = st0 + d0[t];
    }
    __syncthreads();

    if (tot <= STCAP) {
        for (int i = t; i < tot; i += NT) {
            unsigned p = stage[i];
            int l = p & BMASK;
            int s = (int)(p >> SHIFT);
            int pos = atomicAdd((s < TSPLIT) ? &c0[l] : &c1[l], 1);
            col[pos] = s;
        }
    } else {
        for (int r = t; r < nPB; r += NT) {
            int s0 = rss[r], c = rcs[r];
            for (int i = 0; i < c; ++i) {
                unsigned p = part[s0 + i];
                int l = p & BMASK;
                int s = (int)(p >> SHIFT);
                int pos = atomicAdd((s < TSPLIT) ? &c0[l] : &c1[l], 1);
                col[pos] = s;
            }
        }
    }
}

// ---------------- f32 -> bf16 table (stride 32) ----------------
__global__ __launch_bounds__(NT)
void cvt_k(const float* __restrict__ x, unsigned short* __restrict__ xb, int ntot)
{
    int i = blockIdx.x * NT + threadIdx.x;
    if (i < ntot) xb[i] = f2bf(x[i]);
}

// ---------------- gather pass A: sum tile-0 neighbors -> P (f32, stride 32) ----
__global__ __launch_bounds__(NT)
void gA_k(const unsigned short* __restrict__ Hin, const int* __restrict__ row_ptr,
          const int* __restrict__ mptr, const int* __restrict__ col,
          float* __restrict__ P, int n)
{
    const int lane8 = threadIdx.x & 7;
    const int grp   = threadIdx.x >> 3;
    const int node  = blockIdx.x * (NT / 8) + grp;
    if (node >= n) return;
    const int e0 = row_ptr[node];
    const int e1 = mptr[node];
    const ushort4* rows = reinterpret_cast<const ushort4*>(Hin);
    float a0 = 0.f, a1 = 0.f, a2 = 0.f, a3 = 0.f;
    int e = e0;
    for (; e + 3 < e1; e += 4) {
        int s0 = col[e], s1 = col[e + 1], s2 = col[e + 2], s3 = col[e + 3];
        ushort4 v0 = rows[(size_t)s0 * 8 + lane8];
        ushort4 v1 = rows[(size_t)s1 * 8 + lane8];
        ushort4 v2 = rows[(size_t)s2 * 8 + lane8];
        ushort4 v3 = rows[(size_t)s3 * 8 + lane8];
        a0 += bf2f(v0.x) + bf2f(v1.x) + bf2f(v2.x) + bf2f(v3.x);
        a1 += bf2f(v0.y) + bf2f(v1.y) + bf2f(v2.y) + bf2f(v3.y);
        a2 += bf2f(v0.z) + bf2f(v1.z) + bf2f(v2.z) + bf2f(v3.z);
        a3 += bf2f(v0.w) + bf2f(v1.w) + bf2f(v2.w) + bf2f(v3.w);
    }
    for (; e < e1; ++e) {
        ushort4 v0 = rows[(size_t)col[e] * 8 + lane8];
        a0 += bf2f(v0.x); a1 += bf2f(v0.y); a2 += bf2f(v0.z); a3 += bf2f(v0.w);
    }
    reinterpret_cast<float4*>(P + (size_t)node * 32)[lane8] = make_float4(a0, a1, a2, a3);
}

// ---------------- gather pass B: + tile-1, mean, self, dual matmul, act ----
template<int FIN, int FOUT, int ACT>
__global__ __launch_bounds__(NT)
void gB_k(const unsigned short* __restrict__ Hin, const int* __restrict__ row_ptr,
          const int* __restrict__ mptr, const int* __restrict__ col,
          const float* __restrict__ P, const float* __restrict__ Wl,
          const float* __restrict__ Wr, const float* __restrict__ b,
          void* __restrict__ Hout, int n)
{
    constexpr int FS  = 32;
    constexpr int NPB = NT / 8;
    constexpr int GS  = 2 * FS + 4;
    __shared__ float sm[NPB * GS];

    const int lane8 = threadIdx.x & 7;
    const int grp   = threadIdx.x >> 3;
    const int node  = blockIdx.x * NPB + grp;
    const bool valid = node < n;

    if (valid) {
        const int rp0 = row_ptr[node];
        const int rpm = mptr[node];
        const int rp1 = row_ptr[node + 1];
        const ushort4* rows = reinterpret_cast<const ushort4*>(Hin);
        float4 pv = reinterpret_cast<const float4*>(P + (size_t)node * 32)[lane8];
        float a0 = pv.x, a1 = pv.y, a2 = pv.z, a3 = pv.w;
        ushort4 xv = rows[(size_t)node * 8 + lane8];
        int e = rpm;
        for (; e + 3 < rp1; e += 4) {
            int s0 = col[e], s1 = col[e + 1], s2 = col[e + 2], s3 = col[e + 3];
            ushort4 v0 = rows[(size_t)s0 * 8 + lane8];
            ushort4 v1 = rows[(size_t)s1 * 8 + lane8];
            ushort4 v2 = rows[(size_t)s2 * 8 + lane8];
            ushort4 v3 = rows[(size_t)s3 * 8 + lane8];
            a0 += bf2f(v0.x) + bf2f(v1.x) + bf2f(v2.x) + bf2f(v3.x);
            a1 += bf2f(v0.y) + bf2f(v1.y) + bf2f(v2.y) + bf2f(v3.y);
            a2 += bf2f(v0.z) + bf2f(v1.z) + bf2f(v2.z) + bf2f(v3.z);
            a3 += bf2f(v0.w) + bf2f(v1.w) + bf2f(v2.w) + bf2f(v3.w);
        }
        for (; e < rp1; ++e) {
            ushort4 v0 = rows[(size_t)col[e] * 8 + lane8];
            a0 += bf2f(v0.x); a1 += bf2f(v0.y); a2 += bf2f(v0.z); a3 += bf2f(v0.w);
        }
        float invd = 1.0f / fmaxf((float)(rp1 - rp0), 1.0f);
        float* smg = sm + grp * GS;
        smg[4 * lane8 + 0]      = a0 * invd;
        smg[4 * lane8 + 1]      = a1 * invd;
        smg[4 * lane8 + 2]      = a2 * invd;
        smg[4 * lane8 + 3]      = a3 * invd;
        smg[FS + 4 * lane8 + 0] = bf2f(xv.x);
        smg[FS + 4 * lane8 + 1] = bf2f(xv.y);
        smg[FS + 4 * lane8 + 2] = bf2f(xv.z);
        smg[FS + 4 * lane8 + 3] = bf2f(xv.w);
    }
    __syncthreads();

    if (!valid) return;
    const float* smg = sm + grp * GS;

    if constexpr (ACT == 0) {
        unsigned short* out = (unsigned short*)Hout + (size_t)node * FS;
#pragma unroll
        for (int j = 0; j < 4; ++j) {
            int f = lane8 + 8 * j;
            float r = 0.0f;
            if (f < FOUT) {
                float a = b[f];
#pragma unroll
                for (int k = 0; k < FIN; ++k) {
                    a = fmaf(smg[k],      Wl[k * FOUT + f], a);
                    a = fmaf(smg[FS + k], Wr[k * FOUT + f], a);
                }
                r = fmaxf(a, 0.0f);
            }
            out[f] = f2bf(r);
        }
    } else {
        float* out = (float*)Hout + (size_t)node * FOUT;
#pragma unroll
        for (int j = 0; j < (FOUT + 7) / 8; ++j) {
            int f = lane8 + 8 * j;
            if (f < FOUT) {
                float a = b[f];
#pragma unroll
                for (int k = 0; k < FIN; ++k) {
                    a = fmaf(smg[k],      Wl[k * FOUT + f], a);
                    a = fmaf(smg[FS + k], Wr[k * FOUT + f], a);
                }
                out[f] = sigf(a);
            }
        }
    }
}

extern "C" void kernel_launch(void* const* d_in, const int* in_sizes, int n_in,
                              void* d_out, int out_size, void* d_ws, size_t ws_size,
                              hipStream_t stream)
{
    const float* x   = (const float*)d_in[0];
    const int*   ei  = (const int*)d_in[1];
    const float* Wl1 = (const float*)d_in[2];
    const float* Wr1 = (const float*)d_in[3];
    const float* b1  = (const float*)d_in[4];
    const float* Wl2 = (const float*)d_in[5];
    const float* Wr2 = (const float*)d_in[6];
    const float* b2  = (const float*)d_in[7];
    const float* Wl3 = (const float*)d_in[8];
    const float* Wr3 = (const float*)d_in[9];
    const float* b3  = (const float*)d_in[10];

    const int N = in_sizes[0] / 32;
    const int E = in_sizes[1] / 2;
    const int* src = ei;
    const int* dst = ei + E;

    const int nPB = (E + EPB - 1) / EPB;       // 500 (must be <= NPR)
    const int nBK = ((N - 1) >> SHIFT) + 1;    // 782 active buckets
    const int nbG = (N + 31) / 32;
    const int nbC = (N * 32 + NT - 1) / NT;
    const int nbX = (nPB + 31) / 32;           // xpose blocks (16)

    // ---- workspace layout (identical footprint to round 9) ----
    int* runstart = (int*)d_ws;                             // NBK*nPB
    int* runcnt   = runstart + (size_t)NBK * nPB;           // NBK*nPB
    int* totcnt   = runcnt + (size_t)NBK * nPB;             // 1024
    int* fbase    = totcnt + 1024;                          // 1024
    int* row_ptr  = fbase + 1024;                           // N+2
    int* mptr     = row_ptr + (N + 2);                      // N
    size_t off    = 2 * (size_t)NBK * nPB + 2048 + (N + 2) + N;
    off = (off + 3) & ~(size_t)3;                           // 16B align
    int* col      = (int*)d_ws + off;                       // E
    int* runcntT  = col;                                    // nPB*NBK, dead before b_k writes col
    off += E;
    unsigned* part = (unsigned*)((int*)d_ws + off);         // E (dead after b_k)
    float*    P    = (float*)part;                          // N*32 f32 aliases part
    off += E;
    unsigned short* xb  = (unsigned short*)((int*)d_ws + off); // N*32 bf16
    unsigned short* H1b = xb  + (size_t)N * 32;
    unsigned short* H2b = H1b + (size_t)N * 32;

    hipMemsetAsync(totcnt, 0, 1024 * sizeof(int), stream);

    // CSR build: local-sort partition + transpose/scan + tiny scan + finish
    part_k <<<nPB, NT,   0, stream>>>(src, dst, part, runcntT, E, nPB);
    xpose_k<<<nbX, NT,   0, stream>>>(runcntT, runstart, runcnt, totcnt, nPB);
    tscan_k<<<1,   1024, 0, stream>>>(totcnt, fbase);
    b_k    <<<nBK, NT,   0, stream>>>(part, runstart, runcnt, fbase, row_ptr, mptr, col, nPB, N);

    cvt_k  <<<nbC, NT,   0, stream>>>(x, xb, N * 32);

    // 3 layers x (tile-0 pass, tile-1+finish pass)
    gA_k            <<<nbG, NT, 0, stream>>>(xb,  row_ptr, mptr, col, P, N);
    gB_k<32, 24, 0> <<<nbG, NT, 0, stream>>>(xb,  row_ptr, mptr, col, P, Wl1, Wr1, b1, H1b, N);
    gA_k            <<<nbG, NT, 0, stream>>>(H1b, row_ptr, mptr, col, P, N);
    gB_k<24, 24, 0> <<<nbG, NT, 0, stream>>>(H1b, row_ptr, mptr, col, P, Wl2, Wr2, b2, H2b, N);
    gA_k            <<<nbG, NT, 0, stream>>>(H2b, row_ptr, mptr, col, P, N);
    gB_k<24, 12, 1> <<<nbG, NT, 0, stream>>>(H2b, row_ptr, mptr, col, P, Wl3, Wr3, b3, (float*)d_out, N);
}

// Round 11
// 261.031 us; speedup vs baseline: 1.1388x; 1.1388x over previous
//
#include <hip/hip_runtime.h>
#include <cstdint>
#include <cstddef>

#define NT 256
constexpr int SHIFT  = 7;                 // fine bucket = dst >> 7 (128 nodes)
constexpr int NBK    = 1024;              // allocated fine buckets
constexpr int BMASK  = (1 << SHIFT) - 1;  // 127
constexpr int EPB    = 6400;              // edges per partition block (LDS stage)
constexpr int NPR    = 512;               // padded run count (nPB=500)
constexpr int TSPLIT = 50000;             // src tile split (3.2MB bf16 halves)
constexpr int STCAP  = 6144;              // b_k LDS stage capacity

__device__ __forceinline__ float sigf(float v) {
    return 1.0f / (1.0f + __expf(-v));
}
__device__ __forceinline__ float bf2f(unsigned short u) {
    return __uint_as_float((unsigned)u << 16);
}
__device__ __forceinline__ unsigned short f2bf(float f) {   // round-nearest-even
    unsigned u = __float_as_uint(f);
    return (unsigned short)((u + 0x7fffu + ((u >> 16) & 1u)) >> 16);
}

// ---------------- fused partition: LDS local sort, coalesced writes ----------
// Emits BOTH meta arrays block-major (two coalesced 4 KB bursts per block):
//   runcntT[b][f]   = edges of fine-bucket f in this block
//   runstartT[b][f] = b*EPB + exclusive_prefix_f (this block's run start)
__global__ __launch_bounds__(NT)
void part_k(const int* __restrict__ src, const int* __restrict__ dst,
            unsigned* __restrict__ part, int* __restrict__ runcntT,
            int* __restrict__ runstartT, int e_total, int nPB)
{
    __shared__ unsigned stage[EPB];      // 25.6 KB
    __shared__ int hist[NBK];            // 4 KB
    __shared__ int curs[NBK];            // 4 KB
    __shared__ int tsum[NT];             // 1 KB
    const int b    = blockIdx.x;
    const int t    = threadIdx.x;
    const int base = b * EPB;
    const int nh   = min(EPB, e_total - base);

    for (int i = t; i < NBK; i += NT) hist[i] = 0;
    __syncthreads();
    for (int i = t; i < nh; i += NT)
        atomicAdd(&hist[dst[base + i] >> SHIFT], 1);
    __syncthreads();

    // block-major runcnt write: contiguous 4 KB
    for (int i = t; i < NBK; i += NT)
        runcntT[(size_t)b * NBK + i] = hist[i];

    // exclusive scan of hist[1024]: 4 buckets per thread + 256-wide scan
    const int f0 = 4 * t;
    int h0 = hist[f0], h1 = hist[f0 + 1], h2 = hist[f0 + 2], h3 = hist[f0 + 3];
    int incl = h0 + h1 + h2 + h3;
    tsum[t] = incl;
    __syncthreads();
    for (int off = 1; off < NT; off <<= 1) {
        int add = (t >= off) ? tsum[t - off] : 0;
        __syncthreads();
        tsum[t] += add;
        __syncthreads();
    }
    int ex = tsum[t] - incl;             // exclusive over 4-groups
    curs[f0]     = ex;
    curs[f0 + 1] = ex + h0;
    curs[f0 + 2] = ex + h0 + h1;
    curs[f0 + 3] = ex + h0 + h1 + h2;
    // block-major runstart write: thread t writes 4 consecutive dwords
    int* rsp = &runstartT[(size_t)b * NBK + f0];
    rsp[0] = base + ex;
    rsp[1] = base + ex + h0;
    rsp[2] = base + ex + h0 + h1;
    rsp[3] = base + ex + h0 + h1 + h2;
    __syncthreads();

    // scatter into LDS stage in bucket order
    for (int i = t; i < nh; i += NT) {
        int d = dst[base + i];
        int s = src[base + i];
        int f = d >> SHIFT;
        int r = atomicAdd(&curs[f], 1);
        stage[r] = ((unsigned)s << SHIFT) | (unsigned)(d & BMASK);
    }
    __syncthreads();

    // coalesced write-out of the block's sorted region
    for (int i = t; i < nh; i += NT) part[base + i] = stage[i];
}

// ---------------- per-bucket totals: totcnt[f] = sum_b runcntT[b][f] --------
// 32 blocks x 32 f's each; coalesced row reads, no atomics.
__global__ __launch_bounds__(NT)
void csum_k(const int* __restrict__ runcntT, int* __restrict__ totcnt, int nPB)
{
    __shared__ int sm[8][33];
    const int c  = threadIdx.x & 31;
    const int r0 = threadIdx.x >> 5;     // 0..7
    const int f0 = blockIdx.x * 32;
    int acc = 0;
    for (int r = r0; r < nPB; r += 8)
        acc += runcntT[(size_t)r * NBK + f0 + c];
    sm[r0][c] = acc;
    __syncthreads();
    if (threadIdx.x < 32) {
        int s = 0;
#pragma unroll
        for (int i = 0; i < 8; ++i) s += sm[i][threadIdx.x];
        totcnt[f0 + threadIdx.x] = s;
    }
}

// exclusive scan of totcnt[1024] -> fbase[1024] (single block)
__global__ __launch_bounds__(1024)
void tscan_k(const int* __restrict__ totcnt, int* __restrict__ fbase)
{
    __shared__ int s[1024];
    int t = threadIdx.x;
    int v = totcnt[t];
    s[t] = v;
    __syncthreads();
    for (int off = 1; off < 1024; off <<= 1) {
        int add = (t >= off) ? s[t - off] : 0;
        __syncthreads();
        s[t] += add;
        __syncthreads();
    }
    fbase[t] = s[t] - v;
}

// per-bucket: coalesced run copy -> LDS stage; dual histogram/scan -> row_ptr,
// mptr; 2-cursor fill -> col ([tile0 | tile1] per node)
__global__ __launch_bounds__(NT)
void b_k(const unsigned* __restrict__ part, const int* __restrict__ runstartT,
         const int* __restrict__ runcntT, const int* __restrict__ fbase,
         int* __restrict__ row_ptr, int* __restrict__ mptr,
         int* __restrict__ col, int nPB, int n)
{
    constexpr int NB2 = 1 << SHIFT;      // 128
    __shared__ unsigned stage[STCAP];    // 24 KB
    __shared__ int rss[NPR], rcs[NPR], lof[NPR];   // 6 KB
    __shared__ int ssum[NT];
    __shared__ int d0[NB2], dt[NB2], sc[NB2], c0[NB2], c1[NB2];
    const int f = blockIdx.x;
    const int t = threadIdx.x;

    // run metadata (block-major, L2-resident), 2 per thread + exclusive scan
    const int l0 = 2 * t, l1 = 2 * t + 1;
    int rc0 = (l0 < nPB) ? runcntT[(size_t)l0 * NBK + f] : 0;
    int rc1 = (l1 < nPB) ? runcntT[(size_t)l1 * NBK + f] : 0;
    rss[l0] = (l0 < nPB) ? runstartT[(size_t)l0 * NBK + f] : 0;
    rss[l1] = (l1 < nPB) ? runstartT[(size_t)l1 * NBK + f] : 0;
    rcs[l0] = rc0;
    rcs[l1] = rc1;
    int incl = rc0 + rc1;
    ssum[t] = incl;
    __syncthreads();
    for (int off = 1; off < NT; off <<= 1) {
        int add = (t >= off) ? ssum[t - off] : 0;
        __syncthreads();
        ssum[t] += add;
        __syncthreads();
    }
    int ex = ssum[t] - incl;
    lof[l0] = ex;
    lof[l1] = ex + rc0;
    __syncthreads();
    const int tot = ssum[NT - 1];

    if (t < NB2) { d0[t] = 0; dt[t] = 0; }
    __syncthreads();

    if (tot <= STCAP) {
        // coalesced copy: 8 threads per run, 32 runs in flight
        const int lane = t & 7;
        const int rg   = t >> 3;
        for (int chunk = 0; chunk < nPB; chunk += 32) {
            int r = chunk + rg;
            if (r < nPB) {
                int s0 = rss[r], c = rcs[r], lo = lof[r];
                for (int i = lane; i < c; i += 8)
                    stage[lo + i] = part[s0 + i];
            }
        }
        __syncthreads();
        for (int i = t; i < tot; i += NT) {
            unsigned p = stage[i];
            int l = p & BMASK;
            atomicAdd(&dt[l], 1);
            if ((int)(p >> SHIFT) < TSPLIT) atomicAdd(&d0[l], 1);
        }
    } else {
        for (int r = t; r < nPB; r += NT) {
            int s0 = rss[r], c = rcs[r];
            for (int i = 0; i < c; ++i) {
                unsigned p = part[s0 + i];
                int l = p & BMASK;
                atomicAdd(&dt[l], 1);
                if ((int)(p >> SHIFT) < TSPLIT) atomicAdd(&d0[l], 1);
            }
        }
    }
    __syncthreads();

    if (t < NB2) sc[t] = dt[t];
    __syncthreads();
    for (int off = 1; off < NB2; off <<= 1) {
        int add = (t >= off && t < NB2) ? sc[t - off] : 0;
        __syncthreads();
        if (t < NB2) sc[t] += add;
        __syncthreads();
    }
    if (t < NB2) {
        int excl = sc[t] - dt[t];
        int st0  = fbase[f] + excl;
        int node = (f << SHIFT) + t;
        if (node <= n) row_ptr[node] = st0;
        if (node <  n) mptr[node]    = st0 + d0[t];
        c0[t] = st0;
        c1[t] = st0 + d0[t];
    }
    __syncthreads();

    if (tot <= STCAP) {
        for (int i = t; i < tot; i += NT) {
            unsigned p = stage[i];
            int l = p & BMASK;
            int s = (int)(p >> SHIFT);
            int pos = atomicAdd((s < TSPLIT) ? &c0[l] : &c1[l], 1);
            col[pos] = s;
        }
    } else {
        for (int r = t; r < nPB; r += NT) {
            int s0 = rss[r], c = rcs[r];
            for (int i = 0; i < c; ++i) {
                unsigned p = part[s0 + i];
                int l = p & BMASK;
                int s = (int)(p >> SHIFT);
                int pos = atomicAdd((s < TSPLIT) ? &c0[l] : &c1[l], 1);
                col[pos] = s;
            }
        }
    }
}

// ---------------- f32 -> bf16 table (stride 32) ----------------
__global__ __launch_bounds__(NT)
void cvt_k(const float* __restrict__ x, unsigned short* __restrict__ xb, int ntot)
{
    int i = blockIdx.x * NT + threadIdx.x;
    if (i < ntot) xb[i] = f2bf(x[i]);
}

// ---------------- gather pass A: sum tile-0 neighbors -> P (f32, stride 32) ----
__global__ __launch_bounds__(NT)
void gA_k(const unsigned short* __restrict__ Hin, const int* __restrict__ row_ptr,
          const int* __restrict__ mptr, const int* __restrict__ col,
          float* __restrict__ P, int n)
{
    const int lane8 = threadIdx.x & 7;
    const int grp   = threadIdx.x >> 3;
    const int node  = blockIdx.x * (NT / 8) + grp;
    if (node >= n) return;
    const int e0 = row_ptr[node];
    const int e1 = mptr[node];
    const ushort4* rows = reinterpret_cast<const ushort4*>(Hin);
    float a0 = 0.f, a1 = 0.f, a2 = 0.f, a3 = 0.f;
    int e = e0;
    for (; e + 3 < e1; e += 4) {
        int s0 = col[e], s1 = col[e + 1], s2 = col[e + 2], s3 = col[e + 3];
        ushort4 v0 = rows[(size_t)s0 * 8 + lane8];
        ushort4 v1 = rows[(size_t)s1 * 8 + lane8];
        ushort4 v2 = rows[(size_t)s2 * 8 + lane8];
        ushort4 v3 = rows[(size_t)s3 * 8 + lane8];
        a0 += bf2f(v0.x) + bf2f(v1.x) + bf2f(v2.x) + bf2f(v3.x);
        a1 += bf2f(v0.y) + bf2f(v1.y) + bf2f(v2.y) + bf2f(v3.y);
        a2 += bf2f(v0.z) + bf2f(v1.z) + bf2f(v2.z) + bf2f(v3.z);
        a3 += bf2f(v0.w) + bf2f(v1.w) + bf2f(v2.w) + bf2f(v3.w);
    }
    for (; e < e1; ++e) {
        ushort4 v0 = rows[(size_t)col[e] * 8 + lane8];
        a0 += bf2f(v0.x); a1 += bf2f(v0.y); a2 += bf2f(v0.z); a3 += bf2f(v0.w);
    }
    reinterpret_cast<float4*>(P + (size_t)node * 32)[lane8] = make_float4(a0, a1, a2, a3);
}

// ---------------- gather pass B: + tile-1, mean, self, dual matmul, act ----
template<int FIN, int FOUT, int ACT>
__global__ __launch_bounds__(NT)
void gB_k(const unsigned short* __restrict__ Hin, const int* __restrict__ row_ptr,
          const int* __restrict__ mptr, const int* __restrict__ col,
          const float* __restrict__ P, const float* __restrict__ Wl,
          const float* __restrict__ Wr, const float* __restrict__ b,
          void* __restrict__ Hout, int n)
{
    constexpr int FS  = 32;
    constexpr int NPB = NT / 8;
    constexpr int GS  = 2 * FS + 4;
    __shared__ float sm[NPB * GS];

    const int lane8 = threadIdx.x & 7;
    const int grp   = threadIdx.x >> 3;
    const int node  = blockIdx.x * NPB + grp;
    const bool valid = node < n;

    if (valid) {
        const int rp0 = row_ptr[node];
        const int rpm = mptr[node];
        const int rp1 = row_ptr[node + 1];
        const ushort4* rows = reinterpret_cast<const ushort4*>(Hin);
        float4 pv = reinterpret_cast<const float4*>(P + (size_t)node * 32)[lane8];
        float a0 = pv.x, a1 = pv.y, a2 = pv.z, a3 = pv.w;
        ushort4 xv = rows[(size_t)node * 8 + lane8];
        int e = rpm;
        for (; e + 3 < rp1; e += 4) {
            int s0 = col[e], s1 = col[e + 1], s2 = col[e + 2], s3 = col[e + 3];
            ushort4 v0 = rows[(size_t)s0 * 8 + lane8];
            ushort4 v1 = rows[(size_t)s1 * 8 + lane8];
            ushort4 v2 = rows[(size_t)s2 * 8 + lane8];
            ushort4 v3 = rows[(size_t)s3 * 8 + lane8];
            a0 += bf2f(v0.x) + bf2f(v1.x) + bf2f(v2.x) + bf2f(v3.x);
            a1 += bf2f(v0.y) + bf2f(v1.y) + bf2f(v2.y) + bf2f(v3.y);
            a2 += bf2f(v0.z) + bf2f(v1.z) + bf2f(v2.z) + bf2f(v3.z);
            a3 += bf2f(v0.w) + bf2f(v1.w) + bf2f(v2.w) + bf2f(v3.w);
        }
        for (; e < rp1; ++e) {
            ushort4 v0 = rows[(size_t)col[e] * 8 + lane8];
            a0 += bf2f(v0.x); a1 += bf2f(v0.y); a2 += bf2f(v0.z); a3 += bf2f(v0.w);
        }
        float invd = 1.0f / fmaxf((float)(rp1 - rp0), 1.0f);
        float* smg = sm + grp * GS;
        smg[4 * lane8 + 0]      = a0 * invd;
        smg[4 * lane8 + 1]      = a1 * invd;
        smg[4 * lane8 + 2]      = a2 * invd;
        smg[4 * lane8 + 3]      = a3 * invd;
        smg[FS + 4 * lane8 + 0] = bf2f(xv.x);
        smg[FS + 4 * lane8 + 1] = bf2f(xv.y);
        smg[FS + 4 * lane8 + 2] = bf2f(xv.z);
        smg[FS + 4 * lane8 + 3] = bf2f(xv.w);
    }
    __syncthreads();

    if (!valid) return;
    const float* smg = sm + grp * GS;

    if constexpr (ACT == 0) {
        unsigned short* out = (unsigned short*)Hout + (size_t)node * FS;
#pragma unroll
        for (int j = 0; j < 4; ++j) {
            int f = lane8 + 8 * j;
            float r = 0.0f;
            if (f < FOUT) {
                float a = b[f];
#pragma unroll
                for (int k = 0; k < FIN; ++k) {
                    a = fmaf(smg[k],      Wl[k * FOUT + f], a);
                    a = fmaf(smg[FS + k], Wr[k * FOUT + f], a);
                }
                r = fmaxf(a, 0.0f);
            }
            out[f] = f2bf(r);
        }
    } else {
        float* out = (float*)Hout + (size_t)node * FOUT;
#pragma unroll
        for (int j = 0; j < (FOUT + 7) / 8; ++j) {
            int f = lane8 + 8 * j;
            if (f < FOUT) {
                float a = b[f];
#pragma unroll
                for (int k = 0; k < FIN; ++k) {
                    a = fmaf(smg[k],      Wl[k * FOUT + f], a);
                    a = fmaf(smg[FS + k], Wr[k * FOUT + f], a);
                }
                out[f] = sigf(a);
            }
        }
    }
}

extern "C" void kernel_launch(void* const* d_in, const int* in_sizes, int n_in,
                              void* d_out, int out_size, void* d_ws, size_t ws_size,
                              hipStream_t stream)
{
    const float* x   = (const float*)d_in[0];
    const int*   ei  = (const int*)d_in[1];
    const float* Wl1 = (const float*)d_in[2];
    const float* Wr1 = (const float*)d_in[3];
    const float* b1  = (const float*)d_in[4];
    const float* Wl2 = (const float*)d_in[5];
    const float* Wr2 = (const float*)d_in[6];
    const float* b2  = (const float*)d_in[7];
    const float* Wl3 = (const float*)d_in[8];
    const float* Wr3 = (const float*)d_in[9];
    const float* b3  = (const float*)d_in[10];

    const int N = in_sizes[0] / 32;
    const int E = in_sizes[1] / 2;
    const int* src = ei;
    const int* dst = ei + E;

    const int nPB = (E + EPB - 1) / EPB;       // 500 (must be <= NPR)
    const int nBK = ((N - 1) >> SHIFT) + 1;    // 782 active buckets
    const int nbG = (N + 31) / 32;
    const int nbC = (N * 32 + NT - 1) / NT;

    // ---- workspace layout ----
    int* runstartT = (int*)d_ws;                            // nPB*NBK (block-major)
    int* runcntT   = runstartT + (size_t)NBK * nPB;         // nPB*NBK (block-major)
    int* totcnt    = runcntT + (size_t)NBK * nPB;           // 1024
    int* fbase     = totcnt + 1024;                         // 1024
    int* row_ptr   = fbase + 1024;                          // N+2
    int* mptr      = row_ptr + (N + 2);                     // N
    size_t off     = 2 * (size_t)NBK * nPB + 2048 + (N + 2) + N;
    off = (off + 3) & ~(size_t)3;                           // 16B align
    int* col       = (int*)d_ws + off;                      // E
    off += E;
    unsigned* part = (unsigned*)((int*)d_ws + off);         // E (dead after b_k)
    float*    P    = (float*)part;                          // N*32 f32 aliases part
    off += E;
    unsigned short* xb  = (unsigned short*)((int*)d_ws + off); // N*32 bf16
    unsigned short* H1b = xb  + (size_t)N * 32;
    unsigned short* H2b = H1b + (size_t)N * 32;

    // CSR build: local-sort partition + column-sum + tiny scan + finish
    part_k <<<nPB, NT,   0, stream>>>(src, dst, part, runcntT, runstartT, E, nPB);
    csum_k <<<32,  NT,   0, stream>>>(runcntT, totcnt, nPB);
    tscan_k<<<1,   1024, 0, stream>>>(totcnt, fbase);
    b_k    <<<nBK, NT,   0, stream>>>(part, runstartT, runcntT, fbase, row_ptr, mptr, col, nPB, N);

    cvt_k  <<<nbC, NT,   0, stream>>>(x, xb, N * 32);

    // 3 layers x (tile-0 pass, tile-1+finish pass)
    gA_k            <<<nbG, NT, 0, stream>>>(xb,  row_ptr, mptr, col, P, N);
    gB_k<32, 24, 0> <<<nbG, NT, 0, stream>>>(xb,  row_ptr, mptr, col, P, Wl1, Wr1, b1, H1b, N);
    gA_k            <<<nbG, NT, 0, stream>>>(H1b, row_ptr, mptr, col, P, N);
    gB_k<24, 24, 0> <<<nbG, NT, 0, stream>>>(H1b, row_ptr, mptr, col, P, Wl2, Wr2, b2, H2b, N);
    gA_k            <<<nbG, NT, 0, stream>>>(H2b, row_ptr, mptr, col, P, N);
    gB_k<24, 12, 1> <<<nbG, NT, 0, stream>>>(H2b, row_ptr, mptr, col, P, Wl3, Wr3, b3, (float*)d_out, N);
}